// Round 11
// baseline (245.977 us; speedup 1.0000x reference)
//
#include <hip/hip_runtime.h>
#include <math.h>

#define B_ 2
#define N_ 16384
#define V_ 10475
#define J_ 55
#define K_ 6

constexpr int   NB      = 512;       // z-bins per batch
constexpr int   SSTRIDE = 16384;     // sorted-array stride (pos fits 14 bits)
constexpr float ZLO     = -6.0f;
constexpr float ZHI     =  6.0f;
constexpr float HBIN    = (ZHI - ZLO) / (float)NB;
constexpr float INVH    = (float)NB / (ZHI - ZLO);

__device__ __forceinline__ int zbin(float z) {
    int b = (int)floorf((z - ZLO) * INVH);
    return min(max(b, 0), NB - 1);
}

__device__ __forceinline__ double shfl_d(double v, int src) {
    int lo = __double2loint(v), hi = __double2hiint(v);
    lo = __shfl(lo, src, 64);
    hi = __shfl(hi, src, 64);
    return __hiloint2double(hi, lo);
}

// ---------------------------------------------------------------------------
// Build (single kernel, R8/R9-proven): 4 blocks = (batch) x (verts | points).
// LDS histogram -> LDS scan -> LDS-atomic-rank scatter.
// ---------------------------------------------------------------------------
__global__ __launch_bounds__(1024) void build_kernel(const float* __restrict__ pverts,
                                                     const float* __restrict__ x,
                                                     const float* __restrict__ cam,
                                                     float4* __restrict__ pvs,
                                                     int* __restrict__ vidx,
                                                     int* __restrict__ psort,
                                                     int* __restrict__ binStartV) {
    __shared__ int hist[NB];
    __shared__ int cur[NB];
    const int t = threadIdx.x;
    const int b = blockIdx.x >> 1;
    const bool vertsKind = (blockIdx.x & 1) == 0;

    if (t < NB) hist[t] = 0;
    __syncthreads();

    if (vertsKind) {
        for (int i = t; i < V_; i += 1024)
            atomicAdd(&hist[zbin(pverts[((size_t)(b * V_ + i)) * 3 + 2])], 1);
    } else {
        const float cs = cam[b * 3 + 0];
        for (int i = t; i < N_; i += 1024)
            atomicAdd(&hist[zbin(x[((size_t)(b * N_ + i)) * 3 + 2] / cs)], 1);
    }
    __syncthreads();

    for (int off = 1; off < NB; off <<= 1) {
        int v = 0;
        if (t < NB && t >= off) v = hist[t - off];
        __syncthreads();
        if (t < NB) hist[t] += v;
        __syncthreads();
    }
    if (t < NB) {
        int ex = (t == 0) ? 0 : hist[t - 1];
        cur[t] = ex;
        if (vertsKind) binStartV[b * (NB + 1) + t] = ex;
    }
    if (vertsKind && t == 0) binStartV[b * (NB + 1) + NB] = hist[NB - 1];
    __syncthreads();

    if (vertsKind) {
        for (int i = t; i < V_; i += 1024) {
            size_t g = (size_t)(b * V_ + i) * 3;
            float vx = pverts[g], vy = pverts[g + 1], vz = pverts[g + 2];
            int pos = atomicAdd(&cur[zbin(vz)], 1);
            pvs[b * SSTRIDE + pos] = make_float4(vx, vy, vz, vx * vx + vy * vy + vz * vz);
            vidx[b * SSTRIDE + pos] = i;          // batch-local vert id
        }
    } else {
        const float cs = cam[b * 3 + 0];
        for (int i = t; i < N_; i += 1024) {
            float z = x[((size_t)(b * N_ + i)) * 3 + 2] / cs;
            int pos = atomicAdd(&cur[zbin(z)], 1);
            psort[b * N_ + pos] = b * N_ + i;     // global point id
        }
    }
}

// ---------------------------------------------------------------------------
// Fused KNN + epilogue (R9-proven structure). Changes vs R9:
//  (a) register-prefetch pipeline in the scan (tile[i+16] loaded one iter
//      ahead; tile padded +16 so no bounds select — overrun value discarded),
//  (b) expansion chunk 1024 -> 2048 (halves barrier/staging events for the
//      fat tail blocks that set the kernel tail).
// ---------------------------------------------------------------------------
__global__ __launch_bounds__(1024, 4) void knn_kernel(const float4* __restrict__ pvs,
                                                      const int* __restrict__ vidx,
                                                      const int* __restrict__ binStartV,
                                                      const int* __restrict__ psort,
                                                      const float* __restrict__ x,
                                                      const float* __restrict__ cam,
                                                      const float* __restrict__ lbs,
                                                      const float* __restrict__ vt,
                                                      float* __restrict__ out) {
    __shared__ float4 tile[2064];                 // 2048 + 16 prefetch pad
    __shared__ unsigned int cK[16][64][6];
    __shared__ unsigned int eK[64][8];
    __shared__ float gateG;

    const int tid = threadIdx.x, lane = tid & 63, wid = tid >> 6;
    const int b   = blockIdx.x >> 8;              // 256 blocks per batch
    const int blk = blockIdx.x & 255;
    const int pid = psort[b * N_ + blk * 64 + lane];   // global point id

    const float cs = cam[b * 3 + 0], ctx = cam[b * 3 + 1], cty = cam[b * 3 + 2];
    const float Px = x[pid * 3 + 0] / cs - ctx;
    const float Py = x[pid * 3 + 1] / cs - cty;
    const float Pz = x[pid * 3 + 2] / cs;
    const float Ax = -2.f * Px, Ay = -2.f * Py, Az = -2.f * Pz;
    const float Cc = Px * Px + Py * Py + Pz * Pz + 1.0e-4f;  // bias > f32 err

    float zmin = Pz, zmax = Pz;
#pragma unroll
    for (int m = 1; m <= 32; m <<= 1) {
        zmin = fminf(zmin, __shfl_xor(zmin, m, 64));
        zmax = fmaxf(zmax, __shfl_xor(zmax, m, 64));
    }

    const int* bs = binStartV + b * (NB + 1);
    int cbin = zbin(0.5f * (zmin + zmax));
    int center = (bs[cbin] + bs[cbin + 1]) >> 1;
    int lo = center - 1024;
    lo = max(0, min(lo, V_ - 2048));
    int hi = lo + 2048;

    unsigned int bK[6];
#pragma unroll
    for (int t = 0; t < 6; ++t) bK[t] = 0xFFFFFFFFu;

    const float4* pb = pvs + b * SSTRIDE;

    // guarded scan with one-iteration register prefetch of the broadcast read
#define SCAN_RANGE(RL, CNT)                                                    \
    {                                                                          \
        float4 q_ = tile[wid];                                                 \
        for (int i = wid; i < (CNT); i += 16) {                                \
            float4 qn_ = tile[i + 16];       /* prefetch next (pad-safe) */    \
            float d2 = fmaf(Ax, q_.x, fmaf(Ay, q_.y, fmaf(Az, q_.z, Cc + q_.w))); \
            unsigned int key = (__float_as_uint(d2) & 0xFFFFC000u)             \
                             | (unsigned int)((RL) + i);                       \
            if (key < bK[5]) {                                                 \
                unsigned int kk = key;                                         \
                _Pragma("unroll")                                              \
                for (int t = 0; t < 6; ++t) {                                  \
                    unsigned int mn = min(kk, bK[t]);                          \
                    kk = max(kk, bK[t]);                                       \
                    bK[t] = mn;                                                \
                }                                                              \
            }                                                                  \
            q_ = qn_;                                                          \
        }                                                                      \
    }

    // ---- stage + scan center window ----
    tile[tid]        = pb[lo + tid];
    tile[tid + 1024] = pb[lo + 1024 + tid];
    __syncthreads();
    SCAN_RANGE(lo, 2048)

    // ---- gate: per-point union-6th (exact over 16 pools), block max ----
#pragma unroll
    for (int t = 0; t < 6; ++t) cK[wid][lane][t] = bK[t];
    __syncthreads();
    if (wid == 0) {
        unsigned int U[6];
#pragma unroll
        for (int t = 0; t < 6; ++t) U[t] = 0xFFFFFFFFu;
        for (int ss = 0; ss < 16; ++ss)
#pragma unroll
            for (int t = 0; t < 6; ++t) {
                unsigned int kk = cK[ss][lane][t];
                if (kk < U[5]) {
#pragma unroll
                    for (int u = 0; u < 6; ++u) {
                        unsigned int mn = min(kk, U[u]);
                        kk = max(kk, U[u]);
                        U[u] = mn;
                    }
                }
            }
        float g = __uint_as_float(U[5] | 0x3FFFu);   // band top (>=6 real keys)
#pragma unroll
        for (int m = 1; m <= 32; m <<= 1)
            g = fmaxf(g, __shfl_xor(g, m, 64));
        if (lane == 0) gateG = g;
    }
    __syncthreads();
    const float G = gateG;

    // ---- expansion: 2048-vert chunks while frontier bin-edge beats G ----
    while (true) {
        float bl = 3.0e38f, br = 3.0e38f;
        if (lo > 0) {
            int j = zbin(pb[lo - 1].z);
            bl = (j >= NB - 1) ? 0.f
               : fmaxf(0.f, zmin - (ZLO + (float)(j + 1) * HBIN));
        }
        if (hi < V_) {
            int j = zbin(pb[hi].z);
            br = (j <= 0) ? 0.f
               : fmaxf(0.f, (ZLO + (float)j * HBIN) - zmax);
        }
        bool canL = (lo > 0)  && (bl * bl < G);
        bool canR = (hi < V_) && (br * br < G);
        if (!canL && !canR) break;
        bool left = canL && (!canR || bl <= br);
        int rl, rh;
        if (left) { rh = lo; rl = max(0, lo - 2048); lo = rl; }
        else      { rl = hi; rh = min(V_, hi + 2048); hi = rh; }
        __syncthreads();                 // previous tile fully consumed
        int cnt = rh - rl;
        if (tid < cnt) tile[tid] = pb[rl + tid];
        if (tid + 1024 < cnt) tile[tid + 1024] = pb[rl + tid + 1024];
        __syncthreads();
        SCAN_RANGE(rl, cnt)
    }
#undef SCAN_RANGE

    // ---- final merge: wave0 merges 96 -> top-8 keys per point, to LDS ----
    __syncthreads();
#pragma unroll
    for (int t = 0; t < 6; ++t) cK[wid][lane][t] = bK[t];
    __syncthreads();
    if (wid == 0) {
        unsigned int E[8];
#pragma unroll
        for (int t = 0; t < 8; ++t) E[t] = 0xFFFFFFFFu;
        for (int ss = 0; ss < 16; ++ss)
#pragma unroll
            for (int t = 0; t < 6; ++t) {
                unsigned int kk = cK[ss][lane][t];
                if (kk < E[7]) {
#pragma unroll
                    for (int u = 0; u < 8; ++u) {
                        unsigned int mn = min(kk, E[u]);
                        kk = max(kk, E[u]);
                        E[u] = mn;
                    }
                }
            }
#pragma unroll
        for (int t = 0; t < 8; ++t) eK[lane][t] = E[t];
    }
    __syncthreads();

    // ---- fused epilogue: wave wid -> 4 points, one per 16-lane group ----
    const int lj = lane & 15;                    // lane in group
    const int gb = lane & ~15;                   // group base (abs lane)
    const int pl = (wid << 2) + (lane >> 4);     // local point 0..63
    const int pid2 = psort[b * N_ + blk * 64 + pl];

    const float Qx = x[pid2 * 3 + 0] / cs - ctx;
    const float Qy = x[pid2 * 3 + 1] / cs - cty;
    const float Qz = x[pid2 * 3 + 2] / cs;

    double myd = 1.0e300;
    int mygi = 0x7FFFFFFF;
    if (lj < 8) {
        unsigned int key = eK[pl][lj];
        if (key != 0xFFFFFFFFu) {
            int pos = (int)(key & 0x3FFFu);
            mygi = vidx[b * SSTRIDE + pos];
            float4 vq = pb[pos];
            const double csd = (double)cs;
            const double PX = (double)x[pid2 * 3 + 0] / csd - (double)ctx;
            const double PY = (double)x[pid2 * 3 + 1] / csd - (double)cty;
            const double PZ = (double)x[pid2 * 3 + 2] / csd;
            double vx = (double)vq.x, vy = (double)vq.y, vz = (double)vq.z;
            double v2 = vx * vx + vy * vy + vz * vz;
            double P2 = PX * PX + PY * PY + PZ * PZ;
            double dot = PX * vx + PY * vy + PZ * vz;
            myd = P2 + v2 - 2.0 * dot;          // reference expanded form
        }
    }
    double dd[8];
    int ii[8];
#pragma unroll
    for (int t = 0; t < 8; ++t) { dd[t] = shfl_d(myd, gb + t); ii[t] = __shfl(mygi, gb + t, 64); }
#define CE_(a, c) { \
        bool sw_ = (dd[a] > dd[c]) || (dd[a] == dd[c] && ii[a] > ii[c]); \
        double dt_ = sw_ ? dd[a] : dd[c]; dd[a] = sw_ ? dd[c] : dd[a]; dd[c] = dt_; \
        int it_ = sw_ ? ii[a] : ii[c]; ii[a] = sw_ ? ii[c] : ii[a]; ii[c] = it_; }
#pragma unroll
    for (int r = 0; r < 4; ++r) {
        CE_(0, 1) CE_(2, 3) CE_(4, 5) CE_(6, 7)
        CE_(1, 2) CE_(3, 4) CE_(5, 6)
    }
#undef CE_

    const int i0 = (ii[0] < V_) ? ii[0] : 0;
    float r0v[4];
#pragma unroll
    for (int r = 0; r < 4; ++r) {
        int e = lj + (r << 4);
        r0v[r] = (e < J_) ? lbs[i0 * J_ + e] : 0.f;
    }
    float wgt[K_];
    wgt[0] = expf(-fmaxf((float)dd[0], 0.f));     // conf(k=0) == 1 always
#pragma unroll
    for (int k = 1; k < K_; ++k) {
        int gk = (ii[k] < V_) ? ii[k] : 0;
        float sv = 0.f;
#pragma unroll
        for (int r = 0; r < 4; ++r) {
            int e = lj + (r << 4);
            sv += (e < J_) ? fabsf(lbs[gk * J_ + e] - r0v[r]) : 0.f;
        }
#pragma unroll
        for (int m = 1; m <= 8; m <<= 1) sv += __shfl_xor(sv, m, 64);
        // conf > 0.9  <=>  ssum < -WSTD2*ln(0.9) = 0.0021072103
        wgt[k] = (sv < 0.0021072103f) ? expf(-fmaxf((float)dd[k], 0.f)) : 0.f;
    }
    float wsum = ((wgt[0] + wgt[1]) + (wgt[2] + wgt[3])) + (wgt[4] + wgt[5]);
    float inv = 1.f / wsum;

    float acc = 0.f;                               // lj = 4x4 element (r,c)
#pragma unroll
    for (int k = 0; k < K_; ++k) {
        int gk = (ii[k] < V_) ? ii[k] : 0;
        acc += (wgt[k] * inv) * vt[((size_t)(b * V_ + gk)) * 16 + lj];
    }
    const int c = lj & 3;
    float pc = (c == 0) ? Qx : (c == 1) ? Qy : (c == 2) ? Qz : 1.f;
    float part = acc * pc;
    part += __shfl_xor(part, 1, 64);
    part += __shfl_xor(part, 2, 64);
    if (lj == 0)      out[pid2 * 3 + 0] = part;
    else if (lj == 4) out[pid2 * 3 + 1] = part;
    else if (lj == 8) out[pid2 * 3 + 2] = part;
}

// ---------------------------------------------------------------------------
extern "C" void kernel_launch(void* const* d_in, const int* in_sizes, int n_in,
                              void* d_out, int out_size, void* d_ws, size_t ws_size,
                              hipStream_t stream) {
    const float* x      = (const float*)d_in[0];  // [B,N,3]
    const float* cam    = (const float*)d_in[1];  // [B,3]
    const float* lbs    = (const float*)d_in[2];  // [V,J]
    const float* vt     = (const float*)d_in[3];  // [B,V,4,4]
    const float* pverts = (const float*)d_in[4];  // [B,V,3]
    float* out = (float*)d_out;                   // [B,N,3]

    char* ws = (char*)d_ws;
    int* binStartV = (int*)ws;                           // 2*513 ints = 4104 B
    float4* pvs = (float4*)(ws + 4112);                  // 16-aligned; 512 KB
    int* vidx  = (int*)((char*)pvs + (size_t)B_ * SSTRIDE * 16);   // 128 KB
    int* psort = vidx + B_ * SSTRIDE;                    // 128 KB

    build_kernel<<<4, 1024, 0, stream>>>(pverts, x, cam, pvs, vidx, psort, binStartV);
    knn_kernel<<<B_ * (N_ / 64), 1024, 0, stream>>>(pvs, vidx, binStartV, psort,
                                                    x, cam, lbs, vt, out);
}

// Round 12
// 221.334 us; speedup vs baseline: 1.1113x; 1.1113x over previous
//
#include <hip/hip_runtime.h>
#include <math.h>

#define B_ 2
#define N_ 16384
#define V_ 10475
#define J_ 55
#define K_ 6

constexpr int   NB      = 512;       // z-bins per batch
constexpr int   SSTRIDE = 16384;     // sorted-array stride (pos fits 14 bits)
constexpr float ZLO     = -6.0f;
constexpr float ZHI     =  6.0f;
constexpr float HBIN    = (ZHI - ZLO) / (float)NB;
constexpr float INVH    = (float)NB / (ZHI - ZLO);

__device__ __forceinline__ int zbin(float z) {
    int b = (int)floorf((z - ZLO) * INVH);
    return min(max(b, 0), NB - 1);
}

__device__ __forceinline__ double shfl_d(double v, int src) {
    int lo = __double2loint(v), hi = __double2hiint(v);
    lo = __shfl(lo, src, 64);
    hi = __shfl(hi, src, 64);
    return __hiloint2double(hi, lo);
}

// async global->LDS, 16B per lane (wave-uniform LDS base + lane*16 layout)
__device__ __forceinline__ void async16(void* lds, const void* g) {
    __builtin_amdgcn_global_load_lds(
        (const __attribute__((address_space(1))) void*)g,
        (__attribute__((address_space(3))) void*)lds, 16, 0, 0);
}

// ---------------------------------------------------------------------------
// Build (single kernel, R8/R9-proven): 4 blocks = (batch) x (verts | points).
// ---------------------------------------------------------------------------
__global__ __launch_bounds__(1024) void build_kernel(const float* __restrict__ pverts,
                                                     const float* __restrict__ x,
                                                     const float* __restrict__ cam,
                                                     float4* __restrict__ pvs,
                                                     int* __restrict__ vidx,
                                                     int* __restrict__ psort,
                                                     int* __restrict__ binStartV) {
    __shared__ int hist[NB];
    __shared__ int cur[NB];
    const int t = threadIdx.x;
    const int b = blockIdx.x >> 1;
    const bool vertsKind = (blockIdx.x & 1) == 0;

    if (t < NB) hist[t] = 0;
    __syncthreads();

    if (vertsKind) {
        for (int i = t; i < V_; i += 1024)
            atomicAdd(&hist[zbin(pverts[((size_t)(b * V_ + i)) * 3 + 2])], 1);
    } else {
        const float cs = cam[b * 3 + 0];
        for (int i = t; i < N_; i += 1024)
            atomicAdd(&hist[zbin(x[((size_t)(b * N_ + i)) * 3 + 2] / cs)], 1);
    }
    __syncthreads();

    for (int off = 1; off < NB; off <<= 1) {
        int v = 0;
        if (t < NB && t >= off) v = hist[t - off];
        __syncthreads();
        if (t < NB) hist[t] += v;
        __syncthreads();
    }
    if (t < NB) {
        int ex = (t == 0) ? 0 : hist[t - 1];
        cur[t] = ex;
        if (vertsKind) binStartV[b * (NB + 1) + t] = ex;
    }
    if (vertsKind && t == 0) binStartV[b * (NB + 1) + NB] = hist[NB - 1];
    __syncthreads();

    if (vertsKind) {
        for (int i = t; i < V_; i += 1024) {
            size_t g = (size_t)(b * V_ + i) * 3;
            float vx = pverts[g], vy = pverts[g + 1], vz = pverts[g + 2];
            int pos = atomicAdd(&cur[zbin(vz)], 1);
            pvs[b * SSTRIDE + pos] = make_float4(vx, vy, vz, vx * vx + vy * vy + vz * vz);
            vidx[b * SSTRIDE + pos] = i;          // batch-local vert id
        }
    } else {
        const float cs = cam[b * 3 + 0];
        for (int i = t; i < N_; i += 1024) {
            float z = x[((size_t)(b * N_ + i)) * 3 + 2] / cs;
            int pos = atomicAdd(&cur[zbin(z)], 1);
            psort[b * N_ + pos] = b * N_ + i;     // global point id
        }
    }
}

// ---------------------------------------------------------------------------
// Fused KNN + epilogue. R9-proven scan (guarded bubble, center-2048, 1024
// expansion chunks). Changes vs R9:
//  (a) both 96-key merges parallelized over all 16 waves: lane j of each
//      16-lane group loads source-wave j's pool, 4-stage keep-8 bitonic
//      (R5-verified network) -> sorted union top-8 in registers on every
//      lane; no serial wave0 section, no eK round-trip.
//  (b) staging via global_load_lds width=16 (wave-uniform base + lane*16).
// ---------------------------------------------------------------------------
__global__ __launch_bounds__(1024, 8) void knn_kernel(const float4* __restrict__ pvs,
                                                      const int* __restrict__ vidx,
                                                      const int* __restrict__ binStartV,
                                                      const int* __restrict__ psort,
                                                      const float* __restrict__ x,
                                                      const float* __restrict__ cam,
                                                      const float* __restrict__ lbs,
                                                      const float* __restrict__ vt,
                                                      float* __restrict__ out) {
    __shared__ float4 tile[2048];
    __shared__ unsigned int cK[16][64][6];
    __shared__ float sMax[16];

    const int tid = threadIdx.x, lane = tid & 63, wid = tid >> 6;
    const int b   = blockIdx.x >> 8;              // 256 blocks per batch
    const int blk = blockIdx.x & 255;
    const int pid = psort[b * N_ + blk * 64 + lane];   // global point id

    const float cs = cam[b * 3 + 0], ctx = cam[b * 3 + 1], cty = cam[b * 3 + 2];
    const float Px = x[pid * 3 + 0] / cs - ctx;
    const float Py = x[pid * 3 + 1] / cs - cty;
    const float Pz = x[pid * 3 + 2] / cs;
    const float Ax = -2.f * Px, Ay = -2.f * Py, Az = -2.f * Pz;
    const float Cc = Px * Px + Py * Py + Pz * Pz + 1.0e-4f;  // bias > f32 err

    float zmin = Pz, zmax = Pz;
#pragma unroll
    for (int m = 1; m <= 32; m <<= 1) {
        zmin = fminf(zmin, __shfl_xor(zmin, m, 64));
        zmax = fmaxf(zmax, __shfl_xor(zmax, m, 64));
    }

    const int* bs = binStartV + b * (NB + 1);
    int cbin = zbin(0.5f * (zmin + zmax));
    int center = (bs[cbin] + bs[cbin + 1]) >> 1;
    int lo = center - 1024;
    lo = max(0, min(lo, V_ - 2048));
    int hi = lo + 2048;

    unsigned int bK[6];
#pragma unroll
    for (int t = 0; t < 6; ++t) bK[t] = 0xFFFFFFFFu;

    const float4* pb = pvs + b * SSTRIDE;

    // R7/R9-proven guarded scan
#define SCAN_RANGE(RL, CNT)                                                    \
    for (int i = wid; i < (CNT); i += 16) {                                    \
        float4 q = tile[i];            /* wave-uniform addr: broadcast */      \
        float d2 = fmaf(Ax, q.x, fmaf(Ay, q.y, fmaf(Az, q.z, Cc + q.w)));      \
        unsigned int key = (__float_as_uint(d2) & 0xFFFFC000u)                 \
                         | (unsigned int)((RL) + i);                           \
        if (key < bK[5]) {                                                     \
            unsigned int kk = key;                                             \
            _Pragma("unroll")                                                  \
            for (int t = 0; t < 6; ++t) {                                      \
                unsigned int mn = min(kk, bK[t]);                              \
                kk = max(kk, bK[t]);                                           \
                bK[t] = mn;                                                    \
            }                                                                  \
        }                                                                      \
    }

    // parallel merge: sorted union top-8 of point (4*wid + lane/16) into E
#define PMERGE(E)                                                              \
    {                                                                          \
        const int pj = lane & 15, pp = (wid << 2) + (lane >> 4);               \
        _Pragma("unroll")                                                      \
        for (int t = 0; t < 6; ++t) (E)[t] = cK[pj][pp][t];                    \
        (E)[6] = 0xFFFFFFFFu; (E)[7] = 0xFFFFFFFFu;                            \
        _Pragma("unroll")                                                      \
        for (int s = 1; s <= 8; s <<= 1) {                                     \
            unsigned int Bt[8], Cv[8];                                         \
            _Pragma("unroll")                                                  \
            for (int t = 0; t < 8; ++t)                                        \
                Bt[t] = (unsigned int)__shfl_xor((int)(E)[t], s, 64);          \
            _Pragma("unroll")                                                  \
            for (int t = 0; t < 8; ++t) Cv[t] = min((E)[t], Bt[7 - t]);        \
            CEU(0, 4) CEU(1, 5) CEU(2, 6) CEU(3, 7)                            \
            CEU(0, 2) CEU(1, 3) CEU(4, 6) CEU(5, 7)                            \
            CEU(0, 1) CEU(2, 3) CEU(4, 5) CEU(6, 7)                            \
            _Pragma("unroll")                                                  \
            for (int t = 0; t < 8; ++t) (E)[t] = Cv[t];                        \
        }                                                                      \
    }
#define CEU(a, c) { unsigned int mn_ = min(Cv[a], Cv[c]); Cv[c] = max(Cv[a], Cv[c]); Cv[a] = mn_; }

    // ---- stage (async direct-to-LDS) + scan center window ----
    async16(&tile[tid], &pb[lo + tid]);
    async16(&tile[tid + 1024], &pb[lo + 1024 + tid]);
    __syncthreads();
    SCAN_RANGE(lo, 2048)

    // ---- gate: parallel union-6th per point, block max ----
#pragma unroll
    for (int t = 0; t < 6; ++t) cK[wid][lane][t] = bK[t];
    __syncthreads();
    {
        unsigned int E1[8];
        PMERGE(E1)
        float g = __uint_as_float(E1[5] | 0x3FFFu);  // band top (>=6 real keys)
#pragma unroll
        for (int m = 1; m <= 32; m <<= 1)
            g = fmaxf(g, __shfl_xor(g, m, 64));
        if (lane == 0) sMax[wid] = g;
    }
    __syncthreads();
    float G = sMax[0];
#pragma unroll
    for (int t = 1; t < 16; ++t) G = fmaxf(G, sMax[t]);

    // ---- expansion: 1024-vert chunks while frontier bin-edge beats G ----
    while (true) {
        float bl = 3.0e38f, br = 3.0e38f;
        if (lo > 0) {
            int j = zbin(pb[lo - 1].z);
            bl = (j >= NB - 1) ? 0.f
               : fmaxf(0.f, zmin - (ZLO + (float)(j + 1) * HBIN));
        }
        if (hi < V_) {
            int j = zbin(pb[hi].z);
            br = (j <= 0) ? 0.f
               : fmaxf(0.f, (ZLO + (float)j * HBIN) - zmax);
        }
        bool canL = (lo > 0)  && (bl * bl < G);
        bool canR = (hi < V_) && (br * br < G);
        if (!canL && !canR) break;
        bool left = canL && (!canR || bl <= br);
        int rl, rh;
        if (left) { rh = lo; rl = max(0, lo - 1024); lo = rl; }
        else      { rl = hi; rh = min(V_, hi + 1024); hi = rh; }
        __syncthreads();                 // previous tile fully consumed
        int cnt = rh - rl;
        int cntPad = (cnt + 63) & ~63;   // whole waves; reads stay in SSTRIDE
        if (tid < cntPad) async16(&tile[tid], &pb[rl + tid]);
        __syncthreads();
        SCAN_RANGE(rl, cnt)
    }
#undef SCAN_RANGE

    // ---- final: write pools, parallel-merge union top-8 into registers ----
    __syncthreads();                     // all scans + first-merge reads done
#pragma unroll
    for (int t = 0; t < 6; ++t) cK[wid][lane][t] = bK[t];
    __syncthreads();
    unsigned int E[8];
    PMERGE(E)
#undef PMERGE
#undef CEU

    // ---- fused epilogue: wave wid -> 4 points, one per 16-lane group ----
    const int lj = lane & 15;                    // lane in group
    const int gb = lane & ~15;                   // group base (abs lane)
    const int pl = (wid << 2) + (lane >> 4);     // local point 0..63
    const int pid2 = psort[b * N_ + blk * 64 + pl];

    const float Qx = x[pid2 * 3 + 0] / cs - ctx;
    const float Qy = x[pid2 * 3 + 1] / cs - cty;
    const float Qz = x[pid2 * 3 + 2] / cs;

    double myd = 1.0e300;
    int mygi = 0x7FFFFFFF;
    if (lj < 8) {
        unsigned int key = E[lj];
        if (key != 0xFFFFFFFFu) {
            int pos = (int)(key & 0x3FFFu);
            mygi = vidx[b * SSTRIDE + pos];
            float4 vq = pb[pos];
            const double csd = (double)cs;
            const double PX = (double)x[pid2 * 3 + 0] / csd - (double)ctx;
            const double PY = (double)x[pid2 * 3 + 1] / csd - (double)cty;
            const double PZ = (double)x[pid2 * 3 + 2] / csd;
            double vx = (double)vq.x, vy = (double)vq.y, vz = (double)vq.z;
            double v2 = vx * vx + vy * vy + vz * vz;
            double P2 = PX * PX + PY * PY + PZ * PZ;
            double dot = PX * vx + PY * vy + PZ * vz;
            myd = P2 + v2 - 2.0 * dot;          // reference expanded form
        }
    }
    double dd[8];
    int ii[8];
#pragma unroll
    for (int t = 0; t < 8; ++t) { dd[t] = shfl_d(myd, gb + t); ii[t] = __shfl(mygi, gb + t, 64); }
#define CE_(a, c) { \
        bool sw_ = (dd[a] > dd[c]) || (dd[a] == dd[c] && ii[a] > ii[c]); \
        double dt_ = sw_ ? dd[a] : dd[c]; dd[a] = sw_ ? dd[c] : dd[a]; dd[c] = dt_; \
        int it_ = sw_ ? ii[a] : ii[c]; ii[a] = sw_ ? ii[c] : ii[a]; ii[c] = it_; }
#pragma unroll
    for (int r = 0; r < 4; ++r) {
        CE_(0, 1) CE_(2, 3) CE_(4, 5) CE_(6, 7)
        CE_(1, 2) CE_(3, 4) CE_(5, 6)
    }
#undef CE_

    const int i0 = (ii[0] < V_) ? ii[0] : 0;
    float r0v[4];
#pragma unroll
    for (int r = 0; r < 4; ++r) {
        int e = lj + (r << 4);
        r0v[r] = (e < J_) ? lbs[i0 * J_ + e] : 0.f;
    }
    float wgt[K_];
    wgt[0] = expf(-fmaxf((float)dd[0], 0.f));     // conf(k=0) == 1 always
#pragma unroll
    for (int k = 1; k < K_; ++k) {
        int gk = (ii[k] < V_) ? ii[k] : 0;
        float sv = 0.f;
#pragma unroll
        for (int r = 0; r < 4; ++r) {
            int e = lj + (r << 4);
            sv += (e < J_) ? fabsf(lbs[gk * J_ + e] - r0v[r]) : 0.f;
        }
#pragma unroll
        for (int m = 1; m <= 8; m <<= 1) sv += __shfl_xor(sv, m, 64);
        // conf > 0.9  <=>  ssum < -WSTD2*ln(0.9) = 0.0021072103
        wgt[k] = (sv < 0.0021072103f) ? expf(-fmaxf((float)dd[k], 0.f)) : 0.f;
    }
    float wsum = ((wgt[0] + wgt[1]) + (wgt[2] + wgt[3])) + (wgt[4] + wgt[5]);
    float inv = 1.f / wsum;

    float acc = 0.f;                               // lj = 4x4 element (r,c)
#pragma unroll
    for (int k = 0; k < K_; ++k) {
        int gk = (ii[k] < V_) ? ii[k] : 0;
        acc += (wgt[k] * inv) * vt[((size_t)(b * V_ + gk)) * 16 + lj];
    }
    const int c = lj & 3;
    float pc = (c == 0) ? Qx : (c == 1) ? Qy : (c == 2) ? Qz : 1.f;
    float part = acc * pc;
    part += __shfl_xor(part, 1, 64);
    part += __shfl_xor(part, 2, 64);
    if (lj == 0)      out[pid2 * 3 + 0] = part;
    else if (lj == 4) out[pid2 * 3 + 1] = part;
    else if (lj == 8) out[pid2 * 3 + 2] = part;
}

// ---------------------------------------------------------------------------
extern "C" void kernel_launch(void* const* d_in, const int* in_sizes, int n_in,
                              void* d_out, int out_size, void* d_ws, size_t ws_size,
                              hipStream_t stream) {
    const float* x      = (const float*)d_in[0];  // [B,N,3]
    const float* cam    = (const float*)d_in[1];  // [B,3]
    const float* lbs    = (const float*)d_in[2];  // [V,J]
    const float* vt     = (const float*)d_in[3];  // [B,V,4,4]
    const float* pverts = (const float*)d_in[4];  // [B,V,3]
    float* out = (float*)d_out;                   // [B,N,3]

    char* ws = (char*)d_ws;
    int* binStartV = (int*)ws;                           // 2*513 ints = 4104 B
    float4* pvs = (float4*)(ws + 4112);                  // 16-aligned; 512 KB
    int* vidx  = (int*)((char*)pvs + (size_t)B_ * SSTRIDE * 16);   // 128 KB
    int* psort = vidx + B_ * SSTRIDE;                    // 128 KB

    build_kernel<<<4, 1024, 0, stream>>>(pverts, x, cam, pvs, vidx, psort, binStartV);
    knn_kernel<<<B_ * (N_ / 64), 1024, 0, stream>>>(pvs, vidx, binStartV, psort,
                                                    x, cam, lbs, vt, out);
}

// Round 13
// 215.730 us; speedup vs baseline: 1.1402x; 1.0260x over previous
//
#include <hip/hip_runtime.h>
#include <math.h>

#define B_ 2
#define N_ 16384
#define V_ 10475
#define J_ 55
#define K_ 6

constexpr int   NB      = 512;       // z-bins per batch
constexpr int   PB      = 2 * NB;    // point buckets (normal | outlier)
constexpr int   SSTRIDE = 16384;     // sorted-array stride (pos fits 14 bits)
constexpr float ZLO     = -6.0f;
constexpr float ZHI     =  6.0f;
constexpr float HBIN    = (ZHI - ZLO) / (float)NB;
constexpr float INVH    = (float)NB / (ZHI - ZLO);
constexpr float R2OUT   = 5.76f;     // r>2.4 => outlier point (d6 large)

__device__ __forceinline__ int zbin(float z) {
    int b = (int)floorf((z - ZLO) * INVH);
    return min(max(b, 0), NB - 1);
}

__device__ __forceinline__ double shfl_d(double v, int src) {
    int lo = __double2loint(v), hi = __double2hiint(v);
    lo = __shfl(lo, src, 64);
    hi = __shfl(hi, src, 64);
    return __hiloint2double(hi, lo);
}

// async global->LDS, 16B per lane (wave-uniform LDS base + lane*16 layout)
__device__ __forceinline__ void async16(void* lds, const void* g) {
    __builtin_amdgcn_global_load_lds(
        (const __attribute__((address_space(1))) void*)g,
        (__attribute__((address_space(3))) void*)lds, 16, 0, 0);
}

// ---------------------------------------------------------------------------
// Build: 4 blocks = (batch) x (verts | points). Verts keyed by zbin (512
// buckets); points keyed by zbin + NB*outlier (1024 buckets) so wide-window
// points cluster into dedicated blocks instead of poisoning every block's
// gate. Sort order only affects speed, never correctness.
// ---------------------------------------------------------------------------
__global__ __launch_bounds__(1024) void build_kernel(const float* __restrict__ pverts,
                                                     const float* __restrict__ x,
                                                     const float* __restrict__ cam,
                                                     float4* __restrict__ pvs,
                                                     int* __restrict__ vidx,
                                                     int* __restrict__ psort,
                                                     int* __restrict__ binStartV) {
    __shared__ int hist[PB];
    __shared__ int cur[PB];
    const int t = threadIdx.x;
    const int b = blockIdx.x >> 1;
    const bool vertsKind = (blockIdx.x & 1) == 0;

    if (t < PB) hist[t] = 0;
    __syncthreads();

    const float cs = cam[b * 3 + 0], ctx = cam[b * 3 + 1], cty = cam[b * 3 + 2];

    if (vertsKind) {
        for (int i = t; i < V_; i += 1024)
            atomicAdd(&hist[zbin(pverts[((size_t)(b * V_ + i)) * 3 + 2])], 1);
    } else {
        for (int i = t; i < N_; i += 1024) {
            size_t g = (size_t)(b * N_ + i) * 3;
            float px = x[g] / cs - ctx, py = x[g + 1] / cs - cty, pz = x[g + 2] / cs;
            float r2 = px * px + py * py + pz * pz;
            atomicAdd(&hist[zbin(pz) + ((r2 > R2OUT) ? NB : 0)], 1);
        }
    }
    __syncthreads();

    for (int off = 1; off < PB; off <<= 1) {
        int v = 0;
        if (t < PB && t >= off) v = hist[t - off];
        __syncthreads();
        if (t < PB) hist[t] += v;
        __syncthreads();
    }
    if (t < PB) {
        int ex = (t == 0) ? 0 : hist[t - 1];
        cur[t] = ex;
        if (vertsKind && t < NB) binStartV[b * (NB + 1) + t] = ex;
    }
    if (vertsKind && t == 0) binStartV[b * (NB + 1) + NB] = hist[NB - 1];
    __syncthreads();

    if (vertsKind) {
        for (int i = t; i < V_; i += 1024) {
            size_t g = (size_t)(b * V_ + i) * 3;
            float vx = pverts[g], vy = pverts[g + 1], vz = pverts[g + 2];
            int pos = atomicAdd(&cur[zbin(vz)], 1);
            pvs[b * SSTRIDE + pos] = make_float4(vx, vy, vz, vx * vx + vy * vy + vz * vz);
            vidx[b * SSTRIDE + pos] = i;          // batch-local vert id
        }
    } else {
        for (int i = t; i < N_; i += 1024) {
            size_t g = (size_t)(b * N_ + i) * 3;
            float px = x[g] / cs - ctx, py = x[g + 1] / cs - cty, pz = x[g + 2] / cs;
            float r2 = px * px + py * py + pz * pz;
            int pos = atomicAdd(&cur[zbin(pz) + ((r2 > R2OUT) ? NB : 0)], 1);
            psort[b * N_ + pos] = b * N_ + i;     // global point id
        }
    }
}

// ---------------------------------------------------------------------------
// Fused KNN + epilogue (R12-proven). Changes vs R12: cK padded [16][67][6]
// (PMERGE pj-stride 402 = 18 mod 32 -> conflict-light reads).
// ---------------------------------------------------------------------------
__global__ __launch_bounds__(1024, 8) void knn_kernel(const float4* __restrict__ pvs,
                                                      const int* __restrict__ vidx,
                                                      const int* __restrict__ binStartV,
                                                      const int* __restrict__ psort,
                                                      const float* __restrict__ x,
                                                      const float* __restrict__ cam,
                                                      const float* __restrict__ lbs,
                                                      const float* __restrict__ vt,
                                                      float* __restrict__ out) {
    __shared__ float4 tile[2048];
    __shared__ unsigned int cK[16][67][6];        // padded: see header comment
    __shared__ float sMax[16];

    const int tid = threadIdx.x, lane = tid & 63, wid = tid >> 6;
    const int b   = blockIdx.x >> 8;              // 256 blocks per batch
    const int blk = blockIdx.x & 255;
    const int pid = psort[b * N_ + blk * 64 + lane];   // global point id

    const float cs = cam[b * 3 + 0], ctx = cam[b * 3 + 1], cty = cam[b * 3 + 2];
    const float Px = x[pid * 3 + 0] / cs - ctx;
    const float Py = x[pid * 3 + 1] / cs - cty;
    const float Pz = x[pid * 3 + 2] / cs;
    const float Ax = -2.f * Px, Ay = -2.f * Py, Az = -2.f * Pz;
    const float Cc = Px * Px + Py * Py + Pz * Pz + 1.0e-4f;  // bias > f32 err

    float zmin = Pz, zmax = Pz;
#pragma unroll
    for (int m = 1; m <= 32; m <<= 1) {
        zmin = fminf(zmin, __shfl_xor(zmin, m, 64));
        zmax = fmaxf(zmax, __shfl_xor(zmax, m, 64));
    }

    const int* bs = binStartV + b * (NB + 1);
    int cbin = zbin(0.5f * (zmin + zmax));
    int center = (bs[cbin] + bs[cbin + 1]) >> 1;
    int lo = center - 1024;
    lo = max(0, min(lo, V_ - 2048));
    int hi = lo + 2048;

    unsigned int bK[6];
#pragma unroll
    for (int t = 0; t < 6; ++t) bK[t] = 0xFFFFFFFFu;

    const float4* pb = pvs + b * SSTRIDE;

    // R7/R9-proven guarded scan
#define SCAN_RANGE(RL, CNT)                                                    \
    for (int i = wid; i < (CNT); i += 16) {                                    \
        float4 q = tile[i];            /* wave-uniform addr: broadcast */      \
        float d2 = fmaf(Ax, q.x, fmaf(Ay, q.y, fmaf(Az, q.z, Cc + q.w)));      \
        unsigned int key = (__float_as_uint(d2) & 0xFFFFC000u)                 \
                         | (unsigned int)((RL) + i);                           \
        if (key < bK[5]) {                                                     \
            unsigned int kk = key;                                             \
            _Pragma("unroll")                                                  \
            for (int t = 0; t < 6; ++t) {                                      \
                unsigned int mn = min(kk, bK[t]);                              \
                kk = max(kk, bK[t]);                                           \
                bK[t] = mn;                                                    \
            }                                                                  \
        }                                                                      \
    }

    // parallel merge: sorted union top-8 of point (4*wid + lane/16) into E
#define PMERGE(E)                                                              \
    {                                                                          \
        const int pj = lane & 15, pp = (wid << 2) + (lane >> 4);               \
        _Pragma("unroll")                                                      \
        for (int t = 0; t < 6; ++t) (E)[t] = cK[pj][pp][t];                    \
        (E)[6] = 0xFFFFFFFFu; (E)[7] = 0xFFFFFFFFu;                            \
        _Pragma("unroll")                                                      \
        for (int s = 1; s <= 8; s <<= 1) {                                     \
            unsigned int Bt[8], Cv[8];                                         \
            _Pragma("unroll")                                                  \
            for (int t = 0; t < 8; ++t)                                        \
                Bt[t] = (unsigned int)__shfl_xor((int)(E)[t], s, 64);          \
            _Pragma("unroll")                                                  \
            for (int t = 0; t < 8; ++t) Cv[t] = min((E)[t], Bt[7 - t]);        \
            CEU(0, 4) CEU(1, 5) CEU(2, 6) CEU(3, 7)                            \
            CEU(0, 2) CEU(1, 3) CEU(4, 6) CEU(5, 7)                            \
            CEU(0, 1) CEU(2, 3) CEU(4, 5) CEU(6, 7)                            \
            _Pragma("unroll")                                                  \
            for (int t = 0; t < 8; ++t) (E)[t] = Cv[t];                        \
        }                                                                      \
    }
#define CEU(a, c) { unsigned int mn_ = min(Cv[a], Cv[c]); Cv[c] = max(Cv[a], Cv[c]); Cv[a] = mn_; }

    // ---- stage (async direct-to-LDS) + scan center window ----
    async16(&tile[tid], &pb[lo + tid]);
    async16(&tile[tid + 1024], &pb[lo + 1024 + tid]);
    __syncthreads();
    SCAN_RANGE(lo, 2048)

    // ---- gate: parallel union-6th per point, block max ----
#pragma unroll
    for (int t = 0; t < 6; ++t) cK[wid][lane][t] = bK[t];
    __syncthreads();
    {
        unsigned int E1[8];
        PMERGE(E1)
        float g = __uint_as_float(E1[5] | 0x3FFFu);  // band top (>=6 real keys)
#pragma unroll
        for (int m = 1; m <= 32; m <<= 1)
            g = fmaxf(g, __shfl_xor(g, m, 64));
        if (lane == 0) sMax[wid] = g;
    }
    __syncthreads();
    float G = sMax[0];
#pragma unroll
    for (int t = 1; t < 16; ++t) G = fmaxf(G, sMax[t]);

    // ---- expansion: 1024-vert chunks while frontier bin-edge beats G ----
    while (true) {
        float bl = 3.0e38f, br = 3.0e38f;
        if (lo > 0) {
            int j = zbin(pb[lo - 1].z);
            bl = (j >= NB - 1) ? 0.f
               : fmaxf(0.f, zmin - (ZLO + (float)(j + 1) * HBIN));
        }
        if (hi < V_) {
            int j = zbin(pb[hi].z);
            br = (j <= 0) ? 0.f
               : fmaxf(0.f, (ZLO + (float)j * HBIN) - zmax);
        }
        bool canL = (lo > 0)  && (bl * bl < G);
        bool canR = (hi < V_) && (br * br < G);
        if (!canL && !canR) break;
        bool left = canL && (!canR || bl <= br);
        int rl, rh;
        if (left) { rh = lo; rl = max(0, lo - 1024); lo = rl; }
        else      { rl = hi; rh = min(V_, hi + 1024); hi = rh; }
        __syncthreads();                 // previous tile fully consumed
        int cnt = rh - rl;
        int cntPad = (cnt + 63) & ~63;   // whole waves; reads stay in SSTRIDE
        if (tid < cntPad) async16(&tile[tid], &pb[rl + tid]);
        __syncthreads();
        SCAN_RANGE(rl, cnt)
    }
#undef SCAN_RANGE

    // ---- final: write pools, parallel-merge union top-8 into registers ----
    __syncthreads();                     // all scans + first-merge reads done
#pragma unroll
    for (int t = 0; t < 6; ++t) cK[wid][lane][t] = bK[t];
    __syncthreads();
    unsigned int E[8];
    PMERGE(E)
#undef PMERGE
#undef CEU

    // ---- fused epilogue: wave wid -> 4 points, one per 16-lane group ----
    const int lj = lane & 15;                    // lane in group
    const int gb = lane & ~15;                   // group base (abs lane)
    const int pl = (wid << 2) + (lane >> 4);     // local point 0..63
    const int pid2 = psort[b * N_ + blk * 64 + pl];

    const float Qx = x[pid2 * 3 + 0] / cs - ctx;
    const float Qy = x[pid2 * 3 + 1] / cs - cty;
    const float Qz = x[pid2 * 3 + 2] / cs;

    double myd = 1.0e300;
    int mygi = 0x7FFFFFFF;
    if (lj < 8) {
        unsigned int key = E[lj];
        if (key != 0xFFFFFFFFu) {
            int pos = (int)(key & 0x3FFFu);
            mygi = vidx[b * SSTRIDE + pos];
            float4 vq = pb[pos];
            const double csd = (double)cs;
            const double PX = (double)x[pid2 * 3 + 0] / csd - (double)ctx;
            const double PY = (double)x[pid2 * 3 + 1] / csd - (double)cty;
            const double PZ = (double)x[pid2 * 3 + 2] / csd;
            double vx = (double)vq.x, vy = (double)vq.y, vz = (double)vq.z;
            double v2 = vx * vx + vy * vy + vz * vz;
            double P2 = PX * PX + PY * PY + PZ * PZ;
            double dot = PX * vx + PY * vy + PZ * vz;
            myd = P2 + v2 - 2.0 * dot;          // reference expanded form
        }
    }
    double dd[8];
    int ii[8];
#pragma unroll
    for (int t = 0; t < 8; ++t) { dd[t] = shfl_d(myd, gb + t); ii[t] = __shfl(mygi, gb + t, 64); }
#define CE_(a, c) { \
        bool sw_ = (dd[a] > dd[c]) || (dd[a] == dd[c] && ii[a] > ii[c]); \
        double dt_ = sw_ ? dd[a] : dd[c]; dd[a] = sw_ ? dd[c] : dd[a]; dd[c] = dt_; \
        int it_ = sw_ ? ii[a] : ii[c]; ii[a] = sw_ ? ii[c] : ii[a]; ii[c] = it_; }
#pragma unroll
    for (int r = 0; r < 4; ++r) {
        CE_(0, 1) CE_(2, 3) CE_(4, 5) CE_(6, 7)
        CE_(1, 2) CE_(3, 4) CE_(5, 6)
    }
#undef CE_

    const int i0 = (ii[0] < V_) ? ii[0] : 0;
    float r0v[4];
#pragma unroll
    for (int r = 0; r < 4; ++r) {
        int e = lj + (r << 4);
        r0v[r] = (e < J_) ? lbs[i0 * J_ + e] : 0.f;
    }
    float wgt[K_];
    wgt[0] = expf(-fmaxf((float)dd[0], 0.f));     // conf(k=0) == 1 always
#pragma unroll
    for (int k = 1; k < K_; ++k) {
        int gk = (ii[k] < V_) ? ii[k] : 0;
        float sv = 0.f;
#pragma unroll
        for (int r = 0; r < 4; ++r) {
            int e = lj + (r << 4);
            sv += (e < J_) ? fabsf(lbs[gk * J_ + e] - r0v[r]) : 0.f;
        }
#pragma unroll
        for (int m = 1; m <= 8; m <<= 1) sv += __shfl_xor(sv, m, 64);
        // conf > 0.9  <=>  ssum < -WSTD2*ln(0.9) = 0.0021072103
        wgt[k] = (sv < 0.0021072103f) ? expf(-fmaxf((float)dd[k], 0.f)) : 0.f;
    }
    float wsum = ((wgt[0] + wgt[1]) + (wgt[2] + wgt[3])) + (wgt[4] + wgt[5]);
    float inv = 1.f / wsum;

    float acc = 0.f;                               // lj = 4x4 element (r,c)
#pragma unroll
    for (int k = 0; k < K_; ++k) {
        int gk = (ii[k] < V_) ? ii[k] : 0;
        acc += (wgt[k] * inv) * vt[((size_t)(b * V_ + gk)) * 16 + lj];
    }
    const int c = lj & 3;
    float pc = (c == 0) ? Qx : (c == 1) ? Qy : (c == 2) ? Qz : 1.f;
    float part = acc * pc;
    part += __shfl_xor(part, 1, 64);
    part += __shfl_xor(part, 2, 64);
    if (lj == 0)      out[pid2 * 3 + 0] = part;
    else if (lj == 4) out[pid2 * 3 + 1] = part;
    else if (lj == 8) out[pid2 * 3 + 2] = part;
}

// ---------------------------------------------------------------------------
extern "C" void kernel_launch(void* const* d_in, const int* in_sizes, int n_in,
                              void* d_out, int out_size, void* d_ws, size_t ws_size,
                              hipStream_t stream) {
    const float* x      = (const float*)d_in[0];  // [B,N,3]
    const float* cam    = (const float*)d_in[1];  // [B,3]
    const float* lbs    = (const float*)d_in[2];  // [V,J]
    const float* vt     = (const float*)d_in[3];  // [B,V,4,4]
    const float* pverts = (const float*)d_in[4];  // [B,V,3]
    float* out = (float*)d_out;                   // [B,N,3]

    char* ws = (char*)d_ws;
    int* binStartV = (int*)ws;                           // 2*513 ints = 4104 B
    float4* pvs = (float4*)(ws + 4112);                  // 16-aligned; 512 KB
    int* vidx  = (int*)((char*)pvs + (size_t)B_ * SSTRIDE * 16);   // 128 KB
    int* psort = vidx + B_ * SSTRIDE;                    // 128 KB

    build_kernel<<<4, 1024, 0, stream>>>(pverts, x, cam, pvs, vidx, psort, binStartV);
    knn_kernel<<<B_ * (N_ / 64), 1024, 0, stream>>>(pvs, vidx, binStartV, psort,
                                                    x, cam, lbs, vt, out);
}